// Round 7
// baseline (340.234 us; speedup 1.0000x reference)
//
#include <hip/hip_runtime.h>
#include <math.h>

// Problem constants (fixed by setup_inputs)
#define B_   4
#define T_   2048
#define D_   768
#define M_   8192      // B*T
#define GD_  256
#define NH_  4
#define HD_  64

typedef short  s16x8 __attribute__((ext_vector_type(8)));
typedef __bf16 bfx8  __attribute__((ext_vector_type(8)));
typedef float  fx4   __attribute__((ext_vector_type(4)));

#define LOG2E 1.44269504088896f
#define QSCALE (0.125f * LOG2E)      // folded into Q at qkv-GEMM epilogue

__device__ __forceinline__ short f2bf(float f) {   // round-to-nearest-even
  union { float f; unsigned u; } v; v.f = f;
  unsigned r = v.u + 0x7fffu + ((v.u >> 16) & 1u);
  return (short)(r >> 16);
}

struct PW { const short* p0; const short* p1; const short* p2; };
struct PB { const float* p0; const float* p1; const float* p2; };
__device__ __forceinline__ const short* selw(const PW& s, int z) {
  return z == 0 ? s.p0 : (z == 1 ? s.p1 : s.p2);
}
__device__ __forceinline__ const float* selb(const PB& s, int z) {
  return z == 0 ? s.p0 : (z == 1 ? s.p1 : s.p2);
}

// ---------------------------------------------------------------------------
// bf16 MFMA GEMM, register-prefetch pipelined (attention-style).
// C[z] = A[z] @ W[z]^T-stored + bias.  Block 128x64, BK=64, 4 waves (2x2),
// wave tile 64x32.  LDS rows padded to 72 shorts (frag reads 2 lanes/bank).
// AT:   0 = A bf16, 1 = A fp32 (cast to bf16 during staging; used for x).
// MODE: 0 plain (OBF: bf16/fp32 C) | 1 qkv (Q scaled, V -> vtb transposed)
//       | 2 out-proj (C -> ut[g][b][c][t] fp32 transposed)
// ---------------------------------------------------------------------------
template<int AT, int OBF, int MODE>
__global__ __launch_bounds__(256) void gemm_mfma(
    const void* __restrict__ Avoid, long sA, int lda,
    PW Wp, PB Bp, int K,
    void* __restrict__ C, long sC, int ldc,
    void* __restrict__ xtra)
{
  __shared__ short As[128 * 72];   // [m][k+pad]  18.4 KB
  __shared__ short Bs[64 * 72];    // [n][k+pad]   9.2 KB

  const int z = blockIdx.z;
  const short* Ab16 = (const short*)Avoid + (long)z * sA;
  const float* Ab32 = (const float*)Avoid + (long)z * sA;
  const short* Wb = selw(Wp, z);
  const float* bb = selb(Bp, z);

  const int n0 = blockIdx.x * 64;
  const int m0 = blockIdx.y * 128;
  const int tid = threadIdx.x, lane = tid & 63, w = tid >> 6;
  const int wm = w >> 1, wn = w & 1;            // wave tile: rows wm*64, cols wn*32
  const int quad = lane >> 4, mr = lane & 15;

  const int r0 = tid >> 3;            // staging row 0..31
  const int cs = (tid & 7) * 8;       // staging k-offset (8 bf16 = 16B)

  fx4 acc[4][2] = {};
  s16x8 ar[4], br[2];                 // prefetch regs: A rows r0+32g, B rows r0+32h

  auto loadA = [&](int k0) {
#pragma unroll
    for (int gg = 0; gg < 4; ++gg) {
      if (AT) {
        const float* p = Ab32 + (long)(m0 + r0 + 32 * gg) * lda + k0 + cs;
        float4 f0 = *(const float4*)p;
        float4 f1 = *(const float4*)(p + 4);
        short o[8] = { f2bf(f0.x), f2bf(f0.y), f2bf(f0.z), f2bf(f0.w),
                       f2bf(f1.x), f2bf(f1.y), f2bf(f1.z), f2bf(f1.w) };
        ar[gg] = *(s16x8*)o;
      } else {
        ar[gg] = *(const s16x8*)(Ab16 + (long)(m0 + r0 + 32 * gg) * lda + k0 + cs);
      }
    }
  };
  auto loadB = [&](int k0) {
#pragma unroll
    for (int hh = 0; hh < 2; ++hh)
      br[hh] = *(const s16x8*)(Wb + (long)(n0 + r0 + 32 * hh) * K + k0 + cs);
  };

  loadA(0); loadB(0);                 // prologue prefetch

  for (int k0 = 0; k0 < K; k0 += 64) {
    // regs (tile k0) -> LDS
#pragma unroll
    for (int gg = 0; gg < 4; ++gg)
      *(s16x8*)&As[(r0 + 32 * gg) * 72 + cs] = ar[gg];
#pragma unroll
    for (int hh = 0; hh < 2; ++hh)
      *(s16x8*)&Bs[(r0 + 32 * hh) * 72 + cs] = br[hh];
    __syncthreads();

    // prefetch tile k0+64 (in flight during compute below)
    if (k0 + 64 < K) { loadA(k0 + 64); loadB(k0 + 64); }

#pragma unroll
    for (int ks = 0; ks < 2; ++ks) {
      bfx8 af[4], bf[2];
#pragma unroll
      for (int i = 0; i < 4; ++i)
        af[i] = *(const bfx8*)&As[(wm * 64 + i * 16 + mr) * 72 + ks * 32 + quad * 8];
#pragma unroll
      for (int j = 0; j < 2; ++j)
        bf[j] = *(const bfx8*)&Bs[(wn * 32 + j * 16 + mr) * 72 + ks * 32 + quad * 8];
#pragma unroll
      for (int i = 0; i < 4; ++i)
#pragma unroll
        for (int j = 0; j < 2; ++j)
          acc[i][j] = __builtin_amdgcn_mfma_f32_16x16x32_bf16(af[i], bf[j], acc[i][j], 0, 0, 0);
    }
    __syncthreads();
  }

  // epilogue: C/D layout col=lane&15, row=quad*4+reg
  float* Cf = (float*)C + (long)z * sC;
  short* Cs = (short*)C + (long)z * sC;
#pragma unroll
  for (int j = 0; j < 2; ++j) {
    const int col = n0 + wn * 32 + j * 16 + mr;
    const float bvx = bb[col];
#pragma unroll
    for (int i = 0; i < 4; ++i) {
      const int row0 = m0 + wm * 64 + i * 16 + quad * 4;
      if (MODE == 2) {               // u transposed fp32: [g][b][c][t]
        const int rb = row0 >> 11, t0 = row0 & 2047;
        fx4 o;
#pragma unroll
        for (int r = 0; r < 4; ++r) o[r] = acc[i][j][r] + bvx;
        *(fx4*)((float*)xtra + (((long)z * B_ + rb) * GD_ + col) * T_ + t0) = o;
      } else if (MODE == 1 && col >= 512) {   // V -> transposed bf16 buffer
        const int h = (col - 512) >> 6, hd = (col - 512) & 63;
        const int rb = row0 >> 11, t0 = row0 & 2047;
        short o4[4];
#pragma unroll
        for (int r = 0; r < 4; ++r) o4[r] = f2bf(acc[i][j][r] + bvx);
        *(short4*)((short*)xtra + ((((long)z * B_ + rb) * NH_ + h) * HD_ + hd) * T_ + t0) =
            *(short4*)o4;
      } else {
        const float sc = (MODE == 1 && col < 256) ? QSCALE : 1.0f;
#pragma unroll
        for (int r = 0; r < 4; ++r) {
          float v = (acc[i][j][r] + bvx) * sc;
          if (OBF) Cs[(long)(row0 + r) * ldc + col] = f2bf(v);
          else     Cf[(long)(row0 + r) * ldc + col] = v;
        }
      }
    }
  }
}

// ---------------------------------------------------------------------------
// MFMA flash attention, software-pipelined, fixed-shift softmax.
// Q/K in qkv bf16 [g][b][t][768] (cols 0..255 = Q pre-scaled by QSCALE,
// 256..511 = K).  V pre-transposed in vtb[g][b][h][hd][t].
// 1-D grid, heavy q-tiles dispatched first. O overwrites Q slot.
// ---------------------------------------------------------------------------
__global__ __launch_bounds__(256) void flash_attn_mfma(
    short* __restrict__ qkv, const short* __restrict__ vtb)
{
  __shared__ short Ks[64][72];   // [kv row][hd]
  __shared__ short Vs[64][72];   // [hd][kv]
  __shared__ short Ps[64][72];   // [q row][kv col], wave-private slices

  const int bid = blockIdx.x;
  const int qt = 31 - (bid / 48);          // heavy blocks first
  const int combo = bid % 48;
  const int g = combo % 3, bh = combo / 3;
  const int b = bh >> 2, h = bh & 3;

  short* base = qkv + ((size_t)g * M_ + (size_t)b * T_) * D_;
  short*       Qp = base + h * HD_;            // also O destination
  const short* Kp = base + GD_ + h * HD_;
  const short* Vtp = vtb + ((((size_t)g * B_ + b) * NH_ + h) * HD_) * T_;

  const int tid = threadIdx.x, lane = tid & 63, w = tid >> 6;
  const int quad = lane >> 4, mr = lane & 15;
  const int q0 = qt * 64, qr0 = w * 16;

  const int sra = tid >> 3, sc = (tid & 7) * 8;   // staging rows sra, sra+32

  // Q fragments direct from global (A-layout: row qr0+mr, cols ks*32+quad*8)
  bfx8 aq[2];
#pragma unroll
  for (int ks = 0; ks < 2; ++ks)
    aq[ks] = *(const bfx8*)(Qp + (size_t)(q0 + qr0 + mr) * D_ + ks * 32 + quad * 8);

  // prefetch tile 0 into regs (all 16B vector loads)
  s16x8 kreg0 = *(const s16x8*)(Kp + (size_t)sra * D_ + sc);
  s16x8 kreg1 = *(const s16x8*)(Kp + (size_t)(sra + 32) * D_ + sc);
  s16x8 vreg0 = *(const s16x8*)(Vtp + (size_t)sra * T_ + sc);
  s16x8 vreg1 = *(const s16x8*)(Vtp + (size_t)(sra + 32) * T_ + sc);

  fx4 Oa[4] = {};
  float lrow[4] = {0.f, 0.f, 0.f, 0.f};

  for (int kt = 0; kt <= qt; ++kt) {
    // regs (tile kt) -> LDS
    *(s16x8*)&Ks[sra][sc]      = kreg0;
    *(s16x8*)&Ks[sra + 32][sc] = kreg1;
    *(s16x8*)&Vs[sra][sc]      = vreg0;
    *(s16x8*)&Vs[sra + 32][sc] = vreg1;
    __syncthreads();

    // prefetch tile kt+1 (in flight during compute below)
    if (kt < qt) {
      const int kn = (kt + 1) * 64;
      kreg0 = *(const s16x8*)(Kp + (size_t)(kn + sra) * D_ + sc);
      kreg1 = *(const s16x8*)(Kp + (size_t)(kn + sra + 32) * D_ + sc);
      vreg0 = *(const s16x8*)(Vtp + (size_t)sra * T_ + kn + sc);
      vreg1 = *(const s16x8*)(Vtp + (size_t)(sra + 32) * T_ + kn + sc);
    }

    // S = Q K^T  (log2-domain scores; Q pre-scaled)
    fx4 s[4] = {};
#pragma unroll
    for (int ks = 0; ks < 2; ++ks) {
#pragma unroll
      for (int j = 0; j < 4; ++j) {
        bfx8 bk = *(const bfx8*)&Ks[j * 16 + mr][ks * 32 + quad * 8];
        s[j] = __builtin_amdgcn_mfma_f32_16x16x32_bf16(aq[ks], bk, s[j], 0, 0, 0);
      }
    }

    if (kt == qt) {     // causal mask inside diagonal tile
#pragma unroll
      for (int j = 0; j < 4; ++j) {
        int colg = j * 16 + mr;
#pragma unroll
        for (int r = 0; r < 4; ++r)
          if (colg > qr0 + quad * 4 + r) s[j][r] = -1e30f;
      }
    }

    // fixed-shift softmax: p = exp2(s), row-sum into lrow
#pragma unroll
    for (int j = 0; j < 4; ++j)
#pragma unroll
      for (int r = 0; r < 4; ++r) s[j][r] = exp2f(s[j][r]);
#pragma unroll
    for (int r = 0; r < 4; ++r) {
      float sum = (s[0][r] + s[1][r]) + (s[2][r] + s[3][r]);
#pragma unroll
      for (int m2 = 1; m2 < 16; m2 <<= 1) sum += __shfl_xor(sum, m2);
      lrow[r] += sum;
    }

    // P (C-layout) -> Ps bf16 [q row][kv col]; wave-private rows, no barrier
#pragma unroll
    for (int j = 0; j < 4; ++j)
#pragma unroll
      for (int r = 0; r < 4; ++r)
        Ps[qr0 + quad * 4 + r][j * 16 + mr] = f2bf(s[j][r]);

    // O += P @ V
#pragma unroll
    for (int ks = 0; ks < 2; ++ks) {
      bfx8 ap = *(const bfx8*)&Ps[qr0 + mr][ks * 32 + quad * 8];
#pragma unroll
      for (int j = 0; j < 4; ++j) {
        bfx8 bv = *(const bfx8*)&Vs[j * 16 + mr][ks * 32 + quad * 8];
        Oa[j] = __builtin_amdgcn_mfma_f32_16x16x32_bf16(ap, bv, Oa[j], 0, 0, 0);
      }
    }
    __syncthreads();   // all waves done reading Ks/Vs before next overwrite
  }

  // epilogue: normalize, write O (bf16) over Q slot
  float inv[4];
#pragma unroll
  for (int r = 0; r < 4; ++r) inv[r] = 1.0f / lrow[r];
#pragma unroll
  for (int j = 0; j < 4; ++j)
#pragma unroll
    for (int r = 0; r < 4; ++r) {
      int row = q0 + qr0 + quad * 4 + r;
      Qp[(size_t)row * D_ + j * 16 + mr] = f2bf(Oa[j][r] * inv[r]);
    }
}

// ---------------------------------------------------------------------------
// PDE on transposed u_t fp32 [g][b][c][t]; writes ub16 bf16 row-major [t][768].
// Block = (4 cols, b, g); 32 KB LDS; per-thread 32-t register window.
// ---------------------------------------------------------------------------
__device__ __forceinline__ float fhj(float x) { return x - x * x + x * x * x; }

__global__ __launch_bounds__(256) void pde_kernel(
    const float* __restrict__ ut, short* __restrict__ ub)
{
  __shared__ float uu[4 * T_];    // [c][t], 32 KB

  const int cg = blockIdx.x, b = blockIdx.y, g = blockIdx.z;
  const int tid = threadIdx.x;
  const float dt = 0.05f;

  const float* src = ut + (((size_t)g * B_ + b) * GD_ + cg * 4) * T_;

#pragma unroll
  for (int q = 0; q < 8; ++q) {
    int i = (tid + q * 256) * 4;
    *(fx4*)&uu[i] = *(const fx4*)(src + i);
  }
  __syncthreads();

  const int c = tid >> 6;               // 0..3
  const int t0 = (tid & 63) * 32;       // 0..2016
  const int cb = c * T_;

  float uc[36];
#pragma unroll
  for (int q = 0; q < 8; ++q)
    *(fx4*)&uc[2 + q * 4] = *(fx4*)&uu[cb + t0 + q * 4];
  uc[0]  = (t0 >= 2)        ? uu[cb + t0 - 2]  : 0.f;
  uc[1]  = (t0 >= 1)        ? uu[cb + t0 - 1]  : 0.f;
  uc[34] = (t0 + 32 < T_)   ? uu[cb + t0 + 32] : 0.f;
  uc[35] = (t0 + 33 < T_)   ? uu[cb + t0 + 33] : 0.f;

  float wreg[32];
#pragma unroll
  for (int i = 0; i < 32; ++i) wreg[i] = 0.f;

  for (int step = 0; step < 3; ++step) {
    float nu[32];
#pragma unroll
    for (int tt = 0; tt < 32; ++tt) {
      float um2 = uc[tt], um1 = uc[tt + 1], u = uc[tt + 2];
      float up1 = uc[tt + 3], up2 = uc[tt + 4];
      if (g == 0) {
        float d2 = up1 - 2.f * u + um1;
        wreg[tt] += dt * (d2 - sinf(u));
        nu[tt] = u + dt * wreg[tt];
      } else if (g == 1) {
        float d1 = 0.5f * (up1 - um1);
        float d3 = 0.5f * (up2 - 2.f * up1 + 2.f * um1 - um2);
        nu[tt] = u + dt * (-6.f * u * d1 - d3);
      } else {
        float d2f = fhj(up1) - 2.f * fhj(u) + fhj(um1);
        float d4  = up2 - 4.f * up1 + 6.f * u - 4.f * um1 + um2;
        wreg[tt] += dt * (d2f - 0.05f * d4);
        nu[tt] = u + dt * wreg[tt];
      }
    }
    __syncthreads();
#pragma unroll
    for (int q = 0; q < 8; ++q)
      *(fx4*)&uu[cb + t0 + q * 4] = *(fx4*)&nu[q * 4];
    __syncthreads();
#pragma unroll
    for (int i = 0; i < 32; ++i) uc[2 + i] = nu[i];
    if (step < 2) {
      uc[0]  = (t0 >= 2)      ? uu[cb + t0 - 2]  : 0.f;
      uc[1]  = (t0 >= 1)      ? uu[cb + t0 - 1]  : 0.f;
      uc[34] = (t0 + 32 < T_) ? uu[cb + t0 + 32] : 0.f;
      uc[35] = (t0 + 33 < T_) ? uu[cb + t0 + 33] : 0.f;
    }
  }

  short* dst = ub + (size_t)b * T_ * D_ + g * GD_ + cg * 4;
#pragma unroll
  for (int q = 0; q < 8; ++q) {
    int t = tid + q * 256;
    short o4[4];
#pragma unroll
    for (int cc = 0; cc < 4; ++cc) o4[cc] = f2bf(uu[cc * T_ + t]);
    *(short4*)(dst + (size_t)t * D_) = *(short4*)o4;
  }
}

// ---------------------------------------------------------------------------
// Prep: the 8 weight transposes (fp32 [K][N] -> bf16 W^T [N][K]) in one launch.
// ---------------------------------------------------------------------------
struct PrepArgs {
  const float* w[8]; short* wt[8];
  int K[8], N[8];
  int tend[8];
};

__global__ __launch_bounds__(256) void prep_kernel(PrepArgs pa)
{
  const int bid = blockIdx.x, tid = threadIdx.x;
  __shared__ float Ws[32][33];
  int ti = 0;
#pragma unroll
  for (int i = 0; i < 8; ++i) if (bid >= pa.tend[i]) ti = i + 1;
  const int tloc = bid - (ti ? pa.tend[ti - 1] : 0);
  const int K = pa.K[ti], N = pa.N[ti];
  const int ntx = N >> 5;
  const int k0 = (tloc / ntx) * 32, n0 = (tloc % ntx) * 32;
  const float* W = pa.w[ti];
  short* WT = pa.wt[ti];
  const int tx = tid & 31, ty = tid >> 5;

#pragma unroll
  for (int i = 0; i < 4; ++i)
    Ws[ty + 8 * i][tx] = W[(long)(k0 + ty + 8 * i) * N + n0 + tx];
  __syncthreads();
#pragma unroll
  for (int i = 0; i < 4; ++i) {
    int r = ty + 8 * i;
    WT[(long)(n0 + r) * K + k0 + tx] = f2bf(Ws[tx][r]);
  }
}

// ---------------------------------------------------------------------------
// Launch. Workspace (shorts unless noted):
//   [2*MD reserved: u_t fp32 [g][b][c][t] = MD floats lives here; first MD
//    shorts unused, hb at +MD] | qkvb [3*MD] | ub16 [MD] | W^T blobs | vtb [MD]
// ---------------------------------------------------------------------------
extern "C" void kernel_launch(void* const* d_in, const int* in_sizes, int n_in,
                              void* d_out, int out_size, void* d_ws, size_t ws_size,
                              hipStream_t stream)
{
  (void)in_sizes; (void)n_in; (void)out_size; (void)ws_size;

  const float* x         = (const float*)d_in[0];
  const float* in_w      = (const float*)d_in[1];
  const float* in_b      = (const float*)d_in[2];
  const float* sg_qkv_w  = (const float*)d_in[3];
  const float* sg_qkv_b  = (const float*)d_in[4];
  const float* sg_out_w  = (const float*)d_in[5];
  const float* sg_out_b  = (const float*)d_in[6];
  const float* kdv_qkv_w = (const float*)d_in[7];
  const float* kdv_qkv_b = (const float*)d_in[8];
  const float* kdv_out_w = (const float*)d_in[9];
  const float* kdv_out_b = (const float*)d_in[10];
  const float* hj_qkv_w  = (const float*)d_in[11];
  const float* hj_qkv_b  = (const float*)d_in[12];
  const float* hj_out_w  = (const float*)d_in[13];
  const float* hj_out_b  = (const float*)d_in[14];
  const float* out_w     = (const float*)d_in[15];
  const float* out_b     = (const float*)d_in[16];
  float* out = (float*)d_out;

  const size_t MD = (size_t)M_ * D_;     // 6291456
  short* base = (short*)d_ws;
  short* hb   = base + MD;               // h (bf16), second half of u_t region
  float* uf   = (float*)d_ws;            // u_t fp32 overlays [base, hb+MD)
  short* qkvb = base + 2 * MD;
  short* ub16 = qkvb + 3 * MD;
  short* wts  = ub16 + MD;
  short* in_wT  = wts;
  short* qkvT0  = in_wT + 589824;
  short* qkvT1  = qkvT0 + 196608;
  short* qkvT2  = qkvT1 + 196608;
  short* outT0  = qkvT2 + 196608;
  short* outT1  = outT0 + 65536;
  short* outT2  = outT1 + 65536;
  short* out_wT = outT2 + 65536;
  short* vtb    = out_wT + 589824;       // [g][b][h][hd][t], MD shorts

  dim3 blk(256);

  // --- prep: weight transposes only ---
  PrepArgs pa;
  const float* wsrc[8] = { in_w, sg_qkv_w, kdv_qkv_w, hj_qkv_w,
                           sg_out_w, kdv_out_w, hj_out_w, out_w };
  short* wdst[8] = { in_wT, qkvT0, qkvT1, qkvT2, outT0, outT1, outT2, out_wT };
  int Ksz[8] = { 768, 256, 256, 256, 256, 256, 256, 768 };
  int Nsz[8] = { 768, 768, 768, 768, 256, 256, 256, 768 };
  int cum = 0;
  for (int i = 0; i < 8; ++i) {
    pa.w[i] = wsrc[i]; pa.wt[i] = wdst[i]; pa.K[i] = Ksz[i]; pa.N[i] = Nsz[i];
    cum += (Ksz[i] >> 5) * (Nsz[i] >> 5);
    pa.tend[i] = cum;
  }
  prep_kernel<<<dim3((unsigned)cum), blk, 0, stream>>>(pa);

  // 1) h = x @ in_w + in_b   (A = x fp32, cast in staging) -> bf16
  gemm_mfma<1, 1, 0><<<dim3(12, 64, 1), blk, 0, stream>>>(
      x, 0, D_, PW{in_wT, in_wT, in_wT}, PB{in_b, in_b, in_b}, D_,
      hb, 0, D_, nullptr);

  // 2) qkv[g] = h[:,g*256:+256] @ qkv_w_g + b  x3 -> bf16
  //    Q cols pre-scaled by QSCALE; V cols -> vtb transposed
  gemm_mfma<0, 1, 1><<<dim3(12, 64, 3), blk, 0, stream>>>(
      hb, 256, D_,
      PW{qkvT0, qkvT1, qkvT2}, PB{sg_qkv_b, kdv_qkv_b, hj_qkv_b}, GD_,
      qkvb, (long)MD, D_, vtb);

  // 3) causal MFMA flash attention, O -> Q slot (bf16); V from vtb
  flash_attn_mfma<<<dim3(1536), blk, 0, stream>>>(qkvb, vtb);

  // 4) u_t[g][b][c][t] = (O_g @ out_w_g + b)^T   (K=256)x3 -> fp32 transposed
  gemm_mfma<0, 0, 2><<<dim3(4, 64, 3), blk, 0, stream>>>(
      qkvb, (long)MD, D_,
      PW{outT0, outT1, outT2}, PB{sg_out_b, kdv_out_b, hj_out_b}, GD_,
      uf, 0, 0, uf);

  // 5) PDE on u_t (fp32, coalesced) -> ub16 (bf16 row-major)
  pde_kernel<<<dim3(64, 4, 3), blk, 0, stream>>>(uf, ub16);

  // 6) out = u @ out_w + out_b      (8192x768x768) -> fp32
  gemm_mfma<0, 0, 0><<<dim3(12, 64, 1), blk, 0, stream>>>(
      ub16, 0, D_, PW{out_wT, out_wT, out_wT}, PB{out_b, out_b, out_b}, D_,
      out, 0, D_, nullptr);
}

// Round 8
// 332.640 us; speedup vs baseline: 1.0228x; 1.0228x over previous
//
#include <hip/hip_runtime.h>
#include <math.h>

// Problem constants (fixed by setup_inputs)
#define B_   4
#define T_   2048
#define D_   768
#define M_   8192      // B*T
#define GD_  256
#define NH_  4
#define HD_  64

typedef short  s16x8 __attribute__((ext_vector_type(8)));
typedef __bf16 bfx8  __attribute__((ext_vector_type(8)));
typedef float  fx4   __attribute__((ext_vector_type(4)));

#define LOG2E 1.44269504088896f
#define QSCALE (0.125f * LOG2E)      // folded into Q at qkv-GEMM epilogue

__device__ __forceinline__ short f2bf(float f) {   // round-to-nearest-even
  union { float f; unsigned u; } v; v.f = f;
  unsigned r = v.u + 0x7fffu + ((v.u >> 16) & 1u);
  return (short)(r >> 16);
}

struct PW { const short* p0; const short* p1; const short* p2; };
struct PB { const float* p0; const float* p1; const float* p2; };
__device__ __forceinline__ const short* selw(const PW& s, int z) {
  return z == 0 ? s.p0 : (z == 1 ? s.p1 : s.p2);
}
__device__ __forceinline__ const float* selb(const PB& s, int z) {
  return z == 0 ? s.p0 : (z == 1 ? s.p1 : s.p2);
}

// ---------------------------------------------------------------------------
// bf16 MFMA GEMM, register-prefetch pipelined (unchanged from R7).
// Block 128x64, BK=64, 4 waves (2x2), wave tile 64x32. LDS rows pad 72.
// AT: A fp32->bf16 cast in staging. MODE: 0 plain | 1 qkv | 2 out-proj^T.
// ---------------------------------------------------------------------------
template<int AT, int OBF, int MODE>
__global__ __launch_bounds__(256) void gemm_mfma(
    const void* __restrict__ Avoid, long sA, int lda,
    PW Wp, PB Bp, int K,
    void* __restrict__ C, long sC, int ldc,
    void* __restrict__ xtra)
{
  __shared__ short As[128 * 72];
  __shared__ short Bs[64 * 72];

  const int z = blockIdx.z;
  const short* Ab16 = (const short*)Avoid + (long)z * sA;
  const float* Ab32 = (const float*)Avoid + (long)z * sA;
  const short* Wb = selw(Wp, z);
  const float* bb = selb(Bp, z);

  const int n0 = blockIdx.x * 64;
  const int m0 = blockIdx.y * 128;
  const int tid = threadIdx.x, lane = tid & 63, w = tid >> 6;
  const int wm = w >> 1, wn = w & 1;
  const int quad = lane >> 4, mr = lane & 15;

  const int r0 = tid >> 3;
  const int cs = (tid & 7) * 8;

  fx4 acc[4][2] = {};
  s16x8 ar[4], br[2];

  auto loadA = [&](int k0) {
#pragma unroll
    for (int gg = 0; gg < 4; ++gg) {
      if (AT) {
        const float* p = Ab32 + (long)(m0 + r0 + 32 * gg) * lda + k0 + cs;
        float4 f0 = *(const float4*)p;
        float4 f1 = *(const float4*)(p + 4);
        short o[8] = { f2bf(f0.x), f2bf(f0.y), f2bf(f0.z), f2bf(f0.w),
                       f2bf(f1.x), f2bf(f1.y), f2bf(f1.z), f2bf(f1.w) };
        ar[gg] = *(s16x8*)o;
      } else {
        ar[gg] = *(const s16x8*)(Ab16 + (long)(m0 + r0 + 32 * gg) * lda + k0 + cs);
      }
    }
  };
  auto loadB = [&](int k0) {
#pragma unroll
    for (int hh = 0; hh < 2; ++hh)
      br[hh] = *(const s16x8*)(Wb + (long)(n0 + r0 + 32 * hh) * K + k0 + cs);
  };

  loadA(0); loadB(0);

  for (int k0 = 0; k0 < K; k0 += 64) {
#pragma unroll
    for (int gg = 0; gg < 4; ++gg)
      *(s16x8*)&As[(r0 + 32 * gg) * 72 + cs] = ar[gg];
#pragma unroll
    for (int hh = 0; hh < 2; ++hh)
      *(s16x8*)&Bs[(r0 + 32 * hh) * 72 + cs] = br[hh];
    __syncthreads();

    if (k0 + 64 < K) { loadA(k0 + 64); loadB(k0 + 64); }

#pragma unroll
    for (int ks = 0; ks < 2; ++ks) {
      bfx8 af[4], bf[2];
#pragma unroll
      for (int i = 0; i < 4; ++i)
        af[i] = *(const bfx8*)&As[(wm * 64 + i * 16 + mr) * 72 + ks * 32 + quad * 8];
#pragma unroll
      for (int j = 0; j < 2; ++j)
        bf[j] = *(const bfx8*)&Bs[(wn * 32 + j * 16 + mr) * 72 + ks * 32 + quad * 8];
#pragma unroll
      for (int i = 0; i < 4; ++i)
#pragma unroll
        for (int j = 0; j < 2; ++j)
          acc[i][j] = __builtin_amdgcn_mfma_f32_16x16x32_bf16(af[i], bf[j], acc[i][j], 0, 0, 0);
    }
    __syncthreads();
  }

  float* Cf = (float*)C + (long)z * sC;
  short* Cs = (short*)C + (long)z * sC;
#pragma unroll
  for (int j = 0; j < 2; ++j) {
    const int col = n0 + wn * 32 + j * 16 + mr;
    const float bvx = bb[col];
#pragma unroll
    for (int i = 0; i < 4; ++i) {
      const int row0 = m0 + wm * 64 + i * 16 + quad * 4;
      if (MODE == 2) {               // u transposed fp32: [g][b][c][t]
        const int rb = row0 >> 11, t0 = row0 & 2047;
        fx4 o;
#pragma unroll
        for (int r = 0; r < 4; ++r) o[r] = acc[i][j][r] + bvx;
        *(fx4*)((float*)xtra + (((long)z * B_ + rb) * GD_ + col) * T_ + t0) = o;
      } else if (MODE == 1 && col >= 512) {   // V -> transposed bf16 buffer
        const int h = (col - 512) >> 6, hd = (col - 512) & 63;
        const int rb = row0 >> 11, t0 = row0 & 2047;
        short o4[4];
#pragma unroll
        for (int r = 0; r < 4; ++r) o4[r] = f2bf(acc[i][j][r] + bvx);
        *(short4*)((short*)xtra + ((((long)z * B_ + rb) * NH_ + h) * HD_ + hd) * T_ + t0) =
            *(short4*)o4;
      } else {
        const float sc = (MODE == 1 && col < 256) ? QSCALE : 1.0f;
#pragma unroll
        for (int r = 0; r < 4; ++r) {
          float v = (acc[i][j][r] + bvx) * sc;
          if (OBF) Cs[(long)(row0 + r) * ldc + col] = f2bf(v);
          else     Cf[(long)(row0 + r) * ldc + col] = v;
        }
      }
    }
  }
}

// ---------------------------------------------------------------------------
// MFMA flash attention v3: 128 q-rows/block, ones-column MFMA row-sum.
// Q/K in qkv bf16 [g][b][t][768] (Q pre-scaled by QSCALE), V in vtb^T.
// Block = 128 q rows (Q-tile 0..15), kt = 0..2Q+1; wave owns 32 q rows
// (2 row-frags).  Vs rows 64..79 hold bf16 1.0: the 5th PV B-tile computes
// the softmax denominator l via MFMA (C-layout rows match O's rows).
// No cross-lane reduction anywhere.  O overwrites the Q slot.
// ---------------------------------------------------------------------------
__global__ __launch_bounds__(256) void flash_attn_mfma(
    short* __restrict__ qkv, const short* __restrict__ vtb)
{
  __shared__ short Ks[64][72];    // [kv row][hd]
  __shared__ short Vs[80][72];    // [hd][kv]; rows 64..79 = 1.0bf16 (ones)
  __shared__ short Ps[128][72];   // [q row][kv col], wave-private 32-row slices

  const int bid = blockIdx.x;
  const int Q = 15 - (bid / 48);           // heavy blocks first
  const int combo = bid % 48;
  const int g = combo % 3, bh = combo / 3;
  const int b = bh >> 2, h = bh & 3;

  short* base = qkv + ((size_t)g * M_ + (size_t)b * T_) * D_;
  short*       Qp = base + h * HD_;        // also O destination
  const short* Kp = base + GD_ + h * HD_;
  const short* Vtp = vtb + ((((size_t)g * B_ + b) * NH_ + h) * HD_) * T_;

  const int tid = threadIdx.x, lane = tid & 63, w = tid >> 6;
  const int quad = lane >> 4, mr = lane & 15;
  const int q0 = Q * 128, wr = w * 32;

  const int sra = tid >> 3, sc = (tid & 7) * 8;   // staging rows sra, sra+32

  // ones rows 64..79 of Vs (1024 shorts = 128 chunks), written once pre-loop
  if (tid < 128) {
    const short ov = 0x3F80;
    s16x8 one = { ov, ov, ov, ov, ov, ov, ov, ov };
    *(s16x8*)&Vs[64 + (tid >> 3)][(tid & 7) * 8] = one;
  }

  // Q fragments (A-layout): aq[f][ks], row q0+wr+f*16+mr
  bfx8 aq[2][2];
#pragma unroll
  for (int f = 0; f < 2; ++f)
#pragma unroll
    for (int ks = 0; ks < 2; ++ks)
      aq[f][ks] = *(const bfx8*)(Qp + (size_t)(q0 + wr + f * 16 + mr) * D_ +
                                 ks * 32 + quad * 8);

  // prefetch tile 0 into regs (all 16B vector loads)
  s16x8 kreg0 = *(const s16x8*)(Kp + (size_t)sra * D_ + sc);
  s16x8 kreg1 = *(const s16x8*)(Kp + (size_t)(sra + 32) * D_ + sc);
  s16x8 vreg0 = *(const s16x8*)(Vtp + (size_t)sra * T_ + sc);
  s16x8 vreg1 = *(const s16x8*)(Vtp + (size_t)(sra + 32) * T_ + sc);

  fx4 Oa[2][5] = {};    // [row-frag][4 O-tiles + 1 l-tile]

  const int ktmax = 2 * Q + 1;
  for (int kt = 0; kt <= ktmax; ++kt) {
    // regs (tile kt) -> LDS
    *(s16x8*)&Ks[sra][sc]      = kreg0;
    *(s16x8*)&Ks[sra + 32][sc] = kreg1;
    *(s16x8*)&Vs[sra][sc]      = vreg0;
    *(s16x8*)&Vs[sra + 32][sc] = vreg1;
    __syncthreads();

    // prefetch tile kt+1 (in flight during compute below)
    if (kt < ktmax) {
      const int kn = (kt + 1) * 64;
      kreg0 = *(const s16x8*)(Kp + (size_t)(kn + sra) * D_ + sc);
      kreg1 = *(const s16x8*)(Kp + (size_t)(kn + sra + 32) * D_ + sc);
      vreg0 = *(const s16x8*)(Vtp + (size_t)sra * T_ + kn + sc);
      vreg1 = *(const s16x8*)(Vtp + (size_t)(sra + 32) * T_ + kn + sc);
    }

    // S = Q K^T  (two 16-row frags x 64 kv cols)
    fx4 s[2][4] = {};
#pragma unroll
    for (int ks = 0; ks < 2; ++ks) {
      bfx8 bk[4];
#pragma unroll
      for (int j = 0; j < 4; ++j)
        bk[j] = *(const bfx8*)&Ks[j * 16 + mr][ks * 32 + quad * 8];
#pragma unroll
      for (int f = 0; f < 2; ++f)
#pragma unroll
        for (int j = 0; j < 4; ++j)
          s[f][j] = __builtin_amdgcn_mfma_f32_16x16x32_bf16(aq[f][ks], bk[j], s[f][j], 0, 0, 0);
    }

    // causal mask (only the last two kv tiles can cross the diagonal)
    if (kt >= 2 * Q) {
#pragma unroll
      for (int f = 0; f < 2; ++f)
#pragma unroll
        for (int j = 0; j < 4; ++j) {
          const int colg = kt * 64 + j * 16 + mr;
          const int rowg = q0 + wr + f * 16 + quad * 4;
#pragma unroll
          for (int r = 0; r < 4; ++r)
            if (colg > rowg + r) s[f][j][r] = -1e30f;
        }
    }

    // p = exp2(s) -> Ps bf16 [q row][kv col]; wave-private rows, no barrier
#pragma unroll
    for (int f = 0; f < 2; ++f)
#pragma unroll
      for (int j = 0; j < 4; ++j)
#pragma unroll
        for (int r = 0; r < 4; ++r)
          Ps[wr + f * 16 + quad * 4 + r][j * 16 + mr] = f2bf(exp2f(s[f][j][r]));

    // O += P @ V ; l += P @ ones (5th tile)
#pragma unroll
    for (int ks = 0; ks < 2; ++ks) {
      bfx8 ap[2];
#pragma unroll
      for (int f = 0; f < 2; ++f)
        ap[f] = *(const bfx8*)&Ps[wr + f * 16 + mr][ks * 32 + quad * 8];
#pragma unroll
      for (int j = 0; j < 5; ++j) {
        bfx8 bv = *(const bfx8*)&Vs[j * 16 + mr][ks * 32 + quad * 8];
#pragma unroll
        for (int f = 0; f < 2; ++f)
          Oa[f][j] = __builtin_amdgcn_mfma_f32_16x16x32_bf16(ap[f], bv, Oa[f][j], 0, 0, 0);
      }
    }
    __syncthreads();   // all waves done reading Ks/Vs before next overwrite
  }

  // epilogue: normalize by l (= Oa[f][4], same C-layout rows), write O
#pragma unroll
  for (int f = 0; f < 2; ++f)
#pragma unroll
    for (int r = 0; r < 4; ++r) {
      const float inv = 1.0f / Oa[f][4][r];
      const int row = q0 + wr + f * 16 + quad * 4 + r;
#pragma unroll
      for (int j = 0; j < 4; ++j)
        Qp[(size_t)row * D_ + j * 16 + mr] = f2bf(Oa[f][j][r] * inv);
    }
}

// ---------------------------------------------------------------------------
// PDE on transposed u_t fp32 [g][b][c][t]; writes ub16 bf16 row-major [t][768].
// Block = (4 cols, b, g); 32 KB LDS; per-thread 32-t register window.
// ---------------------------------------------------------------------------
__device__ __forceinline__ float fhj(float x) { return x - x * x + x * x * x; }

__global__ __launch_bounds__(256) void pde_kernel(
    const float* __restrict__ ut, short* __restrict__ ub)
{
  __shared__ float uu[4 * T_];    // [c][t], 32 KB

  const int cg = blockIdx.x, b = blockIdx.y, g = blockIdx.z;
  const int tid = threadIdx.x;
  const float dt = 0.05f;

  const float* src = ut + (((size_t)g * B_ + b) * GD_ + cg * 4) * T_;

#pragma unroll
  for (int q = 0; q < 8; ++q) {
    int i = (tid + q * 256) * 4;
    *(fx4*)&uu[i] = *(const fx4*)(src + i);
  }
  __syncthreads();

  const int c = tid >> 6;
  const int t0 = (tid & 63) * 32;
  const int cb = c * T_;

  float uc[36];
#pragma unroll
  for (int q = 0; q < 8; ++q)
    *(fx4*)&uc[2 + q * 4] = *(fx4*)&uu[cb + t0 + q * 4];
  uc[0]  = (t0 >= 2)        ? uu[cb + t0 - 2]  : 0.f;
  uc[1]  = (t0 >= 1)        ? uu[cb + t0 - 1]  : 0.f;
  uc[34] = (t0 + 32 < T_)   ? uu[cb + t0 + 32] : 0.f;
  uc[35] = (t0 + 33 < T_)   ? uu[cb + t0 + 33] : 0.f;

  float wreg[32];
#pragma unroll
  for (int i = 0; i < 32; ++i) wreg[i] = 0.f;

  for (int step = 0; step < 3; ++step) {
    float nu[32];
#pragma unroll
    for (int tt = 0; tt < 32; ++tt) {
      float um2 = uc[tt], um1 = uc[tt + 1], u = uc[tt + 2];
      float up1 = uc[tt + 3], up2 = uc[tt + 4];
      if (g == 0) {
        float d2 = up1 - 2.f * u + um1;
        wreg[tt] += dt * (d2 - sinf(u));
        nu[tt] = u + dt * wreg[tt];
      } else if (g == 1) {
        float d1 = 0.5f * (up1 - um1);
        float d3 = 0.5f * (up2 - 2.f * up1 + 2.f * um1 - um2);
        nu[tt] = u + dt * (-6.f * u * d1 - d3);
      } else {
        float d2f = fhj(up1) - 2.f * fhj(u) + fhj(um1);
        float d4  = up2 - 4.f * up1 + 6.f * u - 4.f * um1 + um2;
        wreg[tt] += dt * (d2f - 0.05f * d4);
        nu[tt] = u + dt * wreg[tt];
      }
    }
    __syncthreads();
#pragma unroll
    for (int q = 0; q < 8; ++q)
      *(fx4*)&uu[cb + t0 + q * 4] = *(fx4*)&nu[q * 4];
    __syncthreads();
#pragma unroll
    for (int i = 0; i < 32; ++i) uc[2 + i] = nu[i];
    if (step < 2) {
      uc[0]  = (t0 >= 2)      ? uu[cb + t0 - 2]  : 0.f;
      uc[1]  = (t0 >= 1)      ? uu[cb + t0 - 1]  : 0.f;
      uc[34] = (t0 + 32 < T_) ? uu[cb + t0 + 32] : 0.f;
      uc[35] = (t0 + 33 < T_) ? uu[cb + t0 + 33] : 0.f;
    }
  }

  short* dst = ub + (size_t)b * T_ * D_ + g * GD_ + cg * 4;
#pragma unroll
  for (int q = 0; q < 8; ++q) {
    int t = tid + q * 256;
    short o4[4];
#pragma unroll
    for (int cc = 0; cc < 4; ++cc) o4[cc] = f2bf(uu[cc * T_ + t]);
    *(short4*)(dst + (size_t)t * D_) = *(short4*)o4;
  }
}

// ---------------------------------------------------------------------------
// Prep: the 8 weight transposes (fp32 [K][N] -> bf16 W^T [N][K]) in one launch.
// ---------------------------------------------------------------------------
struct PrepArgs {
  const float* w[8]; short* wt[8];
  int K[8], N[8];
  int tend[8];
};

__global__ __launch_bounds__(256) void prep_kernel(PrepArgs pa)
{
  const int bid = blockIdx.x, tid = threadIdx.x;
  __shared__ float Ws[32][33];
  int ti = 0;
#pragma unroll
  for (int i = 0; i < 8; ++i) if (bid >= pa.tend[i]) ti = i + 1;
  const int tloc = bid - (ti ? pa.tend[ti - 1] : 0);
  const int K = pa.K[ti], N = pa.N[ti];
  const int ntx = N >> 5;
  const int k0 = (tloc / ntx) * 32, n0 = (tloc % ntx) * 32;
  const float* W = pa.w[ti];
  short* WT = pa.wt[ti];
  const int tx = tid & 31, ty = tid >> 5;

#pragma unroll
  for (int i = 0; i < 4; ++i)
    Ws[ty + 8 * i][tx] = W[(long)(k0 + ty + 8 * i) * N + n0 + tx];
  __syncthreads();
#pragma unroll
  for (int i = 0; i < 4; ++i) {
    int r = ty + 8 * i;
    WT[(long)(n0 + r) * K + k0 + tx] = f2bf(Ws[tx][r]);
  }
}

// ---------------------------------------------------------------------------
// Launch.
// ---------------------------------------------------------------------------
extern "C" void kernel_launch(void* const* d_in, const int* in_sizes, int n_in,
                              void* d_out, int out_size, void* d_ws, size_t ws_size,
                              hipStream_t stream)
{
  (void)in_sizes; (void)n_in; (void)out_size; (void)ws_size;

  const float* x         = (const float*)d_in[0];
  const float* in_w      = (const float*)d_in[1];
  const float* in_b      = (const float*)d_in[2];
  const float* sg_qkv_w  = (const float*)d_in[3];
  const float* sg_qkv_b  = (const float*)d_in[4];
  const float* sg_out_w  = (const float*)d_in[5];
  const float* sg_out_b  = (const float*)d_in[6];
  const float* kdv_qkv_w = (const float*)d_in[7];
  const float* kdv_qkv_b = (const float*)d_in[8];
  const float* kdv_out_w = (const float*)d_in[9];
  const float* kdv_out_b = (const float*)d_in[10];
  const float* hj_qkv_w  = (const float*)d_in[11];
  const float* hj_qkv_b  = (const float*)d_in[12];
  const float* hj_out_w  = (const float*)d_in[13];
  const float* hj_out_b  = (const float*)d_in[14];
  const float* out_w     = (const float*)d_in[15];
  const float* out_b     = (const float*)d_in[16];
  float* out = (float*)d_out;

  const size_t MD = (size_t)M_ * D_;     // 6291456
  short* base = (short*)d_ws;
  short* hb   = base + MD;               // h (bf16), second half of u_t region
  float* uf   = (float*)d_ws;            // u_t fp32 overlays [base, hb+MD)
  short* qkvb = base + 2 * MD;
  short* ub16 = qkvb + 3 * MD;
  short* wts  = ub16 + MD;
  short* in_wT  = wts;
  short* qkvT0  = in_wT + 589824;
  short* qkvT1  = qkvT0 + 196608;
  short* qkvT2  = qkvT1 + 196608;
  short* outT0  = qkvT2 + 196608;
  short* outT1  = outT0 + 65536;
  short* outT2  = outT1 + 65536;
  short* out_wT = outT2 + 65536;
  short* vtb    = out_wT + 589824;       // [g][b][h][hd][t], MD shorts

  dim3 blk(256);

  // --- prep: weight transposes ---
  PrepArgs pa;
  const float* wsrc[8] = { in_w, sg_qkv_w, kdv_qkv_w, hj_qkv_w,
                           sg_out_w, kdv_out_w, hj_out_w, out_w };
  short* wdst[8] = { in_wT, qkvT0, qkvT1, qkvT2, outT0, outT1, outT2, out_wT };
  int Ksz[8] = { 768, 256, 256, 256, 256, 256, 256, 768 };
  int Nsz[8] = { 768, 768, 768, 768, 256, 256, 256, 768 };
  int cum = 0;
  for (int i = 0; i < 8; ++i) {
    pa.w[i] = wsrc[i]; pa.wt[i] = wdst[i]; pa.K[i] = Ksz[i]; pa.N[i] = Nsz[i];
    cum += (Ksz[i] >> 5) * (Nsz[i] >> 5);
    pa.tend[i] = cum;
  }
  prep_kernel<<<dim3((unsigned)cum), blk, 0, stream>>>(pa);

  // 1) h = x @ in_w + in_b   (A = x fp32, cast in staging) -> bf16
  gemm_mfma<1, 1, 0><<<dim3(12, 64, 1), blk, 0, stream>>>(
      x, 0, D_, PW{in_wT, in_wT, in_wT}, PB{in_b, in_b, in_b}, D_,
      hb, 0, D_, nullptr);

  // 2) qkv[g] = h[:,g*256:+256] @ qkv_w_g + b  x3 -> bf16
  //    Q cols pre-scaled by QSCALE; V cols -> vtb transposed
  gemm_mfma<0, 1, 1><<<dim3(12, 64, 3), blk, 0, stream>>>(
      hb, 256, D_,
      PW{qkvT0, qkvT1, qkvT2}, PB{sg_qkv_b, kdv_qkv_b, hj_qkv_b}, GD_,
      qkvb, (long)MD, D_, vtb);

  // 3) causal MFMA flash attention v3 (128 q-rows/block), O -> Q slot
  flash_attn_mfma<<<dim3(768), blk, 0, stream>>>(qkvb, vtb);

  // 4) u_t[g][b][c][t] = (O_g @ out_w_g + b)^T   (K=256)x3 -> fp32 transposed
  gemm_mfma<0, 0, 2><<<dim3(4, 64, 3), blk, 0, stream>>>(
      qkvb, (long)MD, D_,
      PW{outT0, outT1, outT2}, PB{sg_out_b, kdv_out_b, hj_out_b}, GD_,
      uf, 0, 0, uf);

  // 5) PDE on u_t (fp32, coalesced) -> ub16 (bf16 row-major)
  pde_kernel<<<dim3(64, 4, 3), blk, 0, stream>>>(uf, ub16);

  // 6) out = u @ out_w + out_b      (8192x768x768) -> fp32
  gemm_mfma<0, 0, 0><<<dim3(12, 64, 1), blk, 0, stream>>>(
      ub16, 0, D_, PW{out_wT, out_wT, out_wT}, PB{out_b, out_b, out_b}, D_,
      out, 0, D_, nullptr);
}